// Round 1
// baseline (519.997 us; speedup 1.0000x reference)
//
#include <hip/hip_runtime.h>

// Round-2 analysis: LDS-staging kernel was latency-bound, not BW-bound:
// 22% HBM peak with 13% VALUBusy and 20% occupancy (64 KiB LDS -> 2
// blocks/CU = 8 waves/CU), one-shot load->drain->barrier->compute blocks
// leave the memory pipe idle ~half the time.
//
// Round-3 structure: zero LDS, zero barriers, grid-stride streaming (same
// shape as the 6.3 TB/s copy kernel). Work decomposition: 1 lane = 1
// quadrant of 1 image (4 lanes/image, 16 images/wave/iter).
//  - Quadrant p of image g = float4 chunks {cb, cb+2, cb+4, cb+6},
//    cb = (p&1) + 8*(p>>1); chunk cb+2j is patch row j (compile-time!),
//    so the whole 4x16 @ 16x4 first matmul is lane-local with uniform
//    (SGPR) W_conv indices. No data exchange needed for matmul 1.
//  - Second matmul: each lane computes its quadrant's partial of
//    co(16) @ W_linear, then shfl_xor(1) + shfl_xor(2) sums across the
//    4 quadrant lanes (8 DS ops per image-quad).
//  - Lane p==0 of each quad stores the image's float4 result; the 16
//    active lanes cover a contiguous 256 B segment (fully coalesced).
// Occupancy is VGPR-bound only; launch_bounds(256,4) keeps VGPR<=128
// (>=16 waves/CU). 32-B load segments: the other half of each cache line
// is consumed by the adjacent load instr; L1/L2 absorb (L2 has 5x
// headroom over worst-case 2x traffic).

__global__ __launch_bounds__(256, 4) void surrogate_kernel(
    const float* __restrict__ img1, const float* __restrict__ img2,
    const float* __restrict__ Wc,   // (16,4) row-major
    const float* __restrict__ Wl,   // (16,4) row-major
    float* __restrict__ out,
    int B)
{
    const int lane = threadIdx.x & 63;
    const int p    = lane & 3;    // quadrant TL,TR,BL,BR
    const int mloc = lane >> 2;   // image index within wave group (0..15)

    const float4* wc4 = (const float4*)Wc;
    const float4* wl4 = (const float4*)Wl;

    // W_linear rows for this lane's quadrant (held in 16 VGPRs).
    const float4 wl0 = wl4[p * 4 + 0];
    const float4 wl1 = wl4[p * 4 + 1];
    const float4 wl2 = wl4[p * 4 + 2];
    const float4 wl3 = wl4[p * 4 + 3];

    const int wavesPerBlock = blockDim.x >> 6;
    const int waveId = (int)blockIdx.x * wavesPerBlock + ((int)threadIdx.x >> 6);
    const int nWaves = (int)gridDim.x * wavesPerBlock;
    const int total  = 2 * B;                     // images across both inputs
    const int cb     = (p & 1) + ((p >> 1) << 3); // first chunk of quadrant p

    for (int g0 = waveId << 4; g0 < total; g0 += nWaves << 4) {
        // g0 is a multiple of 16 and B % 16 == 0, so the input select is
        // wave-uniform (no straddle within a wave).
        const int g = g0 + mloc;
        const float4* s4 = (g0 < B)
            ? ((const float4*)img1 + ((size_t)g << 4))
            : ((const float4*)img2 + ((size_t)(g - B) << 4));

        float4 v[4];
        v[0] = s4[cb + 0];
        v[1] = s4[cb + 2];
        v[2] = s4[cb + 4];
        v[3] = s4[cb + 6];

        // First matmul: a1[p][0..3] = sum_j sum_x v[j][x] * Wc[4j+x][*]
        // (chunk cb+2j is quadrant row j -> Wc row index compile-time)
        float4 a = make_float4(0.f, 0.f, 0.f, 0.f);
#pragma unroll
        for (int j = 0; j < 4; ++j) {
            const float4 vv = v[j];
            const float4 w0 = wc4[4 * j + 0];
            const float4 w1 = wc4[4 * j + 1];
            const float4 w2 = wc4[4 * j + 2];
            const float4 w3 = wc4[4 * j + 3];
            a.x = fmaf(vv.x, w0.x, a.x); a.y = fmaf(vv.x, w0.y, a.y);
            a.z = fmaf(vv.x, w0.z, a.z); a.w = fmaf(vv.x, w0.w, a.w);
            a.x = fmaf(vv.y, w1.x, a.x); a.y = fmaf(vv.y, w1.y, a.y);
            a.z = fmaf(vv.y, w1.z, a.z); a.w = fmaf(vv.y, w1.w, a.w);
            a.x = fmaf(vv.z, w2.x, a.x); a.y = fmaf(vv.z, w2.y, a.y);
            a.z = fmaf(vv.z, w2.z, a.z); a.w = fmaf(vv.z, w2.w, a.w);
            a.x = fmaf(vv.w, w3.x, a.x); a.y = fmaf(vv.w, w3.y, a.y);
            a.z = fmaf(vv.w, w3.z, a.z); a.w = fmaf(vv.w, w3.w, a.w);
        }

        // relu -> /64 -> clip : lane holds co[4p + 0..3]
        float4 co;
        co.x = fminf(fmaxf(fmaxf(a.x, 0.f) * 0.015625f, -128.f), 127.f);
        co.y = fminf(fmaxf(fmaxf(a.y, 0.f) * 0.015625f, -128.f), 127.f);
        co.z = fminf(fmaxf(fmaxf(a.z, 0.f) * 0.015625f, -128.f), 127.f);
        co.w = fminf(fmaxf(fmaxf(a.w, 0.f) * 0.015625f, -128.f), 127.f);

        // Second matmul partial: rows 4p..4p+3 of W_linear
        float4 t;
        t.x = fmaf(co.x, wl0.x, fmaf(co.y, wl1.x, fmaf(co.z, wl2.x, co.w * wl3.x)));
        t.y = fmaf(co.x, wl0.y, fmaf(co.y, wl1.y, fmaf(co.z, wl2.y, co.w * wl3.y)));
        t.z = fmaf(co.x, wl0.z, fmaf(co.y, wl1.z, fmaf(co.z, wl2.z, co.w * wl3.z)));
        t.w = fmaf(co.x, wl0.w, fmaf(co.y, wl1.w, fmaf(co.z, wl2.w, co.w * wl3.w)));

        // Reduce across the 4 quadrant lanes (bits 0,1 of lane id).
        t.x += __shfl_xor(t.x, 1); t.y += __shfl_xor(t.y, 1);
        t.z += __shfl_xor(t.z, 1); t.w += __shfl_xor(t.w, 1);
        t.x += __shfl_xor(t.x, 2); t.y += __shfl_xor(t.y, 2);
        t.z += __shfl_xor(t.z, 2); t.w += __shfl_xor(t.w, 2);

        if (p == 0) {
            float4 o;
            o.x = fminf(fmaxf(t.x * 0.015625f, -128.f), 127.f);
            o.y = fminf(fmaxf(t.y * 0.015625f, -128.f), 127.f);
            o.z = fminf(fmaxf(t.z * 0.015625f, -128.f), 127.f);
            o.w = fminf(fmaxf(t.w * 0.015625f, -128.f), 127.f);
            // out is (res1 | res2) back-to-back: flat float4 index == g.
            ((float4*)out)[g] = o;
        }
    }
}

extern "C" void kernel_launch(void* const* d_in, const int* in_sizes, int n_in,
                              void* d_out, int out_size, void* d_ws, size_t ws_size,
                              hipStream_t stream) {
    const float* img1 = (const float*)d_in[0];
    const float* img2 = (const float*)d_in[1];
    const float* Wc   = (const float*)d_in[2];
    const float* Wl   = (const float*)d_in[3];
    float* out = (float*)d_out;

    const int B = in_sizes[0] / 64;   // images per input (1<<20)
    // Grid-stride: 2048 blocks x 4 waves = 8192 waves, 16 images/wave/iter
    // -> 16 iterations at B = 1<<20. Cap for small B.
    int blocks = (2 * B + 63) / 64;
    if (blocks > 2048) blocks = 2048;
    hipLaunchKernelGGL(surrogate_kernel, dim3(blocks), dim3(256), 0, stream,
                       img1, img2, Wc, Wl, out, B);
}